// Round 1
// baseline (901.636 us; speedup 1.0000x reference)
//
#include <hip/hip_runtime.h>
#include <stdint.h>

typedef __attribute__((ext_vector_type(8))) short short8;
typedef __attribute__((ext_vector_type(4))) float floatx4;

#define SEQ    2048
#define HID    4096
#define NHEAD  32
#define HDIMV  128
#define PROJN  12288

__device__ __forceinline__ unsigned short f2bf(float f) {
  union { float f; unsigned u; } v; v.f = f;
  unsigned r = (v.u + 0x7fffu + ((v.u >> 16) & 1u)) >> 16;
  return (unsigned short)r;
}

// -------------------- async 16B global->LDS --------------------
__device__ __forceinline__ void g2l16(const void* g, void* l) {
  __builtin_amdgcn_global_load_lds(
      (const __attribute__((address_space(1))) void*)g,
      (__attribute__((address_space(3))) void*)l, 16, 0, 0);
}

// ---------- pack fp32 [R x K] row-major -> bf16 tile images ----------
// Tile (rp, kt) = 128 rows x 64 k, chunk-major: elem (r,c) at
// tile*8192 + ((c>>3)*128 + r)*8 + (c&7). Rows < scale_rows get multiplied by
// scale (used to fold the softmax 1/sqrt(d)*log2(e) into w_pack's Q rows).
__global__ __launch_bounds__(256) void pack_fp32(const float* __restrict__ src,
                                                 unsigned short* __restrict__ dst, int K,
                                                 int scale_rows, float scale) {
  const int rp = blockIdx.x, kt = blockIdx.y, t = threadIdx.x;
  const long tb = ((long)rp * gridDim.y + kt) * 8192;
#pragma unroll
  for (int j = 0; j < 4; j++) {
    int ch = t + j * 256;
    int r = ch & 127, cc = ch >> 7;
    float sc = (rp * 128 + r < scale_rows) ? scale : 1.0f;
    const float* s = src + (long)(rp * 128 + r) * K + kt * 64 + cc * 8;
    float4 a = *(const float4*)s;
    float4 b = *(const float4*)(s + 4);
    short8 o;
    o[0] = (short)f2bf(a.x * sc); o[1] = (short)f2bf(a.y * sc);
    o[2] = (short)f2bf(a.z * sc); o[3] = (short)f2bf(a.w * sc);
    o[4] = (short)f2bf(b.x * sc); o[5] = (short)f2bf(b.y * sc);
    o[6] = (short)f2bf(b.z * sc); o[7] = (short)f2bf(b.w * sc);
    *(short8*)(dst + tb + ch * 8) = o;
  }
}

// ---------- pack Q,K slices of proj -> per-(h,tile) 128x128 chunk-major ----------
__global__ __launch_bounds__(256) void pack_qk(const unsigned short* __restrict__ proj,
                                               unsigned short* __restrict__ dstQ,
                                               unsigned short* __restrict__ dstK) {
  const int st = blockIdx.x, h = blockIdx.y, t = threadIdx.x;
  const long tb = ((long)(h * 16 + st)) * 16384;
#pragma unroll
  for (int j = 0; j < 8; j++) {
    int ch = t + j * 256;
    int r = ch & 127, cc = ch >> 7;
    long so = (long)(st * 128 + r) * PROJN + h * 128 + cc * 8;
    *(short8*)(dstQ + tb + ch * 8) = *(const short8*)(proj + so);
    *(short8*)(dstK + tb + ch * 8) = *(const short8*)(proj + so + HID);
  }
}

// ---------- pack V^T: proj V-slice -> per-(h,tile) chunk-major with row=d, k=s ----------
__global__ __launch_bounds__(256) void pack_v(const unsigned short* __restrict__ proj,
                                              unsigned short* __restrict__ Vf) {
  __shared__ unsigned short T[128 * 136];
  const int st = blockIdx.x, h = blockIdx.y, t = threadIdx.x;
  const long tb = ((long)(h * 16 + st)) * 16384;
  const unsigned short* src = proj + (long)(st * 128) * PROJN + 2 * HID + h * 128;
#pragma unroll
  for (int it = 0; it < 8; it++) {
    int idx = t * 8 + it * 2048;
    int r = idx >> 7, c = idx & 127;
    *(short8*)(T + r * 136 + c) = *(const short8*)(src + (long)r * PROJN + c);
  }
  __syncthreads();
#pragma unroll
  for (int pass = 0; pass < 4; pass++) {
    int d = (t >> 3) + pass * 32;
    int sc = t & 7;
    short8 lo, hi;
#pragma unroll
    for (int j = 0; j < 8; j++) lo[j] = (short)T[(sc * 16 + j) * 136 + d];
#pragma unroll
    for (int j = 0; j < 8; j++) hi[j] = (short)T[(sc * 16 + 8 + j) * 136 + d];
    *(short8*)(Vf + tb + ((sc * 2) * 128 + d) * 8) = lo;
    *(short8*)(Vf + tb + ((sc * 2 + 1) * 128 + d) * 8) = hi;
  }
}

// -------------------- NT GEMM on packed tiles --------------------
template<int OUT_F32>
__global__ __launch_bounds__(256, 4) void gemm_pk(
    const unsigned short* __restrict__ Ap,
    const unsigned short* __restrict__ Bp,
    void* __restrict__ C, int N, int K) {
  __shared__ __align__(16) unsigned short As[8192];
  __shared__ __align__(16) unsigned short Bs[8192];
  const int t = threadIdx.x;
  const int wave = t >> 6, lane = t & 63;
  const int bid = blockIdx.x;
  const int xcd = bid & 7;
  const int li = bid >> 3;
  const int mi = li & 15;
  const int ni = (li >> 4) * 8 + xcd;
  const int KT = K >> 6;
  const unsigned short* at = Ap + (long)mi * KT * 8192 + t * 8;
  const unsigned short* bt = Bp + (long)ni * KT * 8192 + t * 8;
  unsigned short* asl = As + wave * 512;
  unsigned short* bsl = Bs + wave * 512;

  const int mw = (wave >> 1) * 64;
  const int nw = (wave & 1) * 64;
  const int lq = lane & 15, lg = lane >> 4;

  floatx4 zero = {0.f, 0.f, 0.f, 0.f};
  floatx4 acc[4][4];
  for (int i = 0; i < 4; i++)
    for (int j = 0; j < 4; j++) acc[i][j] = zero;

  for (int kt = 0; kt < KT; kt++) {
    __syncthreads();
    const unsigned short* ak = at + (long)kt * 8192;
    const unsigned short* bk = bt + (long)kt * 8192;
#pragma unroll
    for (int j = 0; j < 4; j++) g2l16(ak + j * 2048, asl + j * 2048);
#pragma unroll
    for (int j = 0; j < 4; j++) g2l16(bk + j * 2048, bsl + j * 2048);
    __syncthreads();
#pragma unroll
    for (int kk = 0; kk < 2; kk++) {
      const int ch = (kk * 4 + lg) * 1024;
      short8 af[4], bfr[4];
#pragma unroll
      for (int i = 0; i < 4; i++)
        af[i] = *(const short8*)(As + ch + (mw + i * 16 + lq) * 8);
#pragma unroll
      for (int j = 0; j < 4; j++)
        bfr[j] = *(const short8*)(Bs + ch + (nw + j * 16 + lq) * 8);
#pragma unroll
      for (int i = 0; i < 4; i++)
#pragma unroll
        for (int j = 0; j < 4; j++)
          acc[i][j] = __builtin_amdgcn_mfma_f32_16x16x32_bf16(af[i], bfr[j], acc[i][j], 0, 0, 0);
    }
  }

  const int row0 = mi * 128 + mw + lg * 4;
  const int col0 = ni * 128 + nw + lq;
  if (OUT_F32) {
    float* Cf = (float*)C;
#pragma unroll
    for (int i = 0; i < 4; i++)
#pragma unroll
      for (int j = 0; j < 4; j++)
#pragma unroll
        for (int r = 0; r < 4; r++)
          Cf[(long)(row0 + i * 16 + r) * N + col0 + j * 16] = acc[i][j][r];
  } else {
    unsigned short* Cb = (unsigned short*)C;
#pragma unroll
    for (int i = 0; i < 4; i++)
#pragma unroll
      for (int j = 0; j < 4; j++)
#pragma unroll
        for (int r = 0; r < 4; r++)
          Cb[(long)(row0 + i * 16 + r) * N + col0 + j * 16] = f2bf(acc[i][j][r]);
  }
}

// -------------------- causal flash attention --------------------
// No K/V LDS staging: per-head K/V images (1 MB) are L2-resident on the owning
// XCD (h = bx&31 -> all 16 q-tiles of head h land on XCD h%8; 4 heads x 1 MB =
// 4 MB = per-XCD L2). MFMA K/V fragments are read directly from the packed
// global images (chunk-major => 4x256B contiguous runs per fragment batch).
// LDS = 32 KB (wave-private P round-trip only), zero barriers,
// __launch_bounds__(256,2) -> 2 blocks/CU, all 512 blocks co-resident.
// qt pairing: idx<8 -> qt=15-idx (heavy), idx>=8 -> qt=idx-8 (light); the two
// co-resident blocks on a CU sum to 16 kv-iters (balanced), and the ordering
// degrades to heavy-first if occupancy drops to 1 block/CU.
__global__ __launch_bounds__(256, 2) void attn_kernel(
    const unsigned short* __restrict__ Qf,
    const unsigned short* __restrict__ Kf,
    const unsigned short* __restrict__ Vf,
    unsigned short* __restrict__ aop) {
  __shared__ __align__(16) unsigned short Ps[16384];
  const int bx = blockIdx.x;
  const int h = bx & 31;
  const int idx = bx >> 5;
  const int qt = (idx < 8) ? (15 - idx) : (idx - 8);
  const int t = threadIdx.x, wave = t >> 6, lane = t & 63;
  const int lq = lane & 15, lg = lane >> 4;
  const int wOff = wave * 32;

  // Q fragments: coalesced global reads from packed image (Q pre-scaled)
  const unsigned short* qb = Qf + ((long)(h * 16 + qt)) * 16384;
  short8 qf[2][4];
#pragma unroll
  for (int i = 0; i < 2; i++)
#pragma unroll
    for (int kk = 0; kk < 4; kk++)
      qf[i][kk] = *(const short8*)(qb + ((kk * 4 + lg) * 128 + wOff + i * 16 + lq) * 8);

  float mraw[2][4], lsum[2][4];
  floatx4 zero = {0.f, 0.f, 0.f, 0.f};
  floatx4 o[2][8];
#pragma unroll
  for (int i = 0; i < 2; i++)
#pragma unroll
    for (int r = 0; r < 4; r++) { mraw[i][r] = -INFINITY; lsum[i][r] = 0.f; }
#pragma unroll
  for (int i = 0; i < 2; i++)
#pragma unroll
    for (int j = 0; j < 8; j++) o[i][j] = zero;

  const unsigned short* kb0 = Kf + ((long)h * 16) * 16384;
  const unsigned short* vb0 = Vf + ((long)h * 16) * 16384;

  for (int kv = 0; kv <= qt; kv++) {
    const bool diag = (kv == qt);
    const unsigned short* kb = kb0 + (long)kv * 16384;
    const unsigned short* vb = vb0 + (long)kv * 16384;

    // S = Q K^T (already in log2 domain via pre-scaled Q); K frags direct from L2
    floatx4 s[2][8];
#pragma unroll
    for (int i = 0; i < 2; i++)
#pragma unroll
      for (int j = 0; j < 8; j++) s[i][j] = zero;
#pragma unroll
    for (int kk = 0; kk < 4; kk++) {
      short8 bfr[8];
#pragma unroll
      for (int j = 0; j < 8; j++)
        bfr[j] = *(const short8*)(kb + ((kk * 4 + lg) * 128 + j * 16 + lq) * 8);
      __builtin_amdgcn_s_setprio(1);
#pragma unroll
      for (int i = 0; i < 2; i++)
#pragma unroll
        for (int j = 0; j < 8; j++)
          s[i][j] = __builtin_amdgcn_mfma_f32_16x16x32_bf16(qf[i][kk], bfr[j], s[i][j], 0, 0, 0);
      __builtin_amdgcn_s_setprio(0);
    }

    if (diag) {
#pragma unroll
      for (int i = 0; i < 2; i++)
#pragma unroll
        for (int r = 0; r < 4; r++) {
          int qrow = qt * 128 + wOff + i * 16 + lg * 4 + r;
#pragma unroll
          for (int j = 0; j < 8; j++)
            if (kv * 128 + j * 16 + lq > qrow) s[i][j][r] = -INFINITY;
        }
    }

    // online softmax (log2 domain; rows lane-local, reduce over 16 col-lanes)
    float alpha_[2][4];
#pragma unroll
    for (int i = 0; i < 2; i++) {
#pragma unroll
      for (int r = 0; r < 4; r++) {
        float mx = s[i][0][r];
#pragma unroll
        for (int j = 1; j < 8; j++) mx = fmaxf(mx, s[i][j][r]);
#pragma unroll
        for (int d = 1; d < 16; d <<= 1) mx = fmaxf(mx, __shfl_xor(mx, d, 64));
        float mnew = fmaxf(mraw[i][r], mx);
        float al = exp2f(mraw[i][r] - mnew);
        float ps = 0.f;
#pragma unroll
        for (int j = 0; j < 8; j++) {
          float p = exp2f(s[i][j][r] - mnew);
          s[i][j][r] = p;
          ps += p;
        }
#pragma unroll
        for (int d = 1; d < 16; d <<= 1) ps += __shfl_xor(ps, d, 64);
        lsum[i][r] = lsum[i][r] * al + ps;
        mraw[i][r] = mnew;
        alpha_[i][r] = al;
      }
    }
#pragma unroll
    for (int i = 0; i < 2; i++)
#pragma unroll
      for (int j = 0; j < 8; j++)
#pragma unroll
        for (int r = 0; r < 4; r++) o[i][j][r] *= alpha_[i][r];

    // P (C-layout regs) -> chunk-major LDS, wave-private rows, no barrier
#pragma unroll
    for (int i = 0; i < 2; i++)
#pragma unroll
      for (int r = 0; r < 4; r++) {
        int prow = wOff + i * 16 + lg * 4 + r;
#pragma unroll
        for (int j = 0; j < 8; j++)
          Ps[((j * 2 + (lq >> 3)) * 128 + prow) * 8 + (lq & 7)] = f2bf(s[i][j][r]);
      }

    // O += P V (A-frags from own P rows, B-frags direct from packed V image)
#pragma unroll
    for (int kk = 0; kk < 4; kk++) {
      short8 pf[2], vf[8];
#pragma unroll
      for (int i = 0; i < 2; i++)
        pf[i] = *(const short8*)(Ps + ((kk * 4 + lg) * 128 + wOff + i * 16 + lq) * 8);
#pragma unroll
      for (int j = 0; j < 8; j++)
        vf[j] = *(const short8*)(vb + ((kk * 4 + lg) * 128 + j * 16 + lq) * 8);
      __builtin_amdgcn_s_setprio(1);
#pragma unroll
      for (int i = 0; i < 2; i++)
#pragma unroll
        for (int j = 0; j < 8; j++)
          o[i][j] = __builtin_amdgcn_mfma_f32_16x16x32_bf16(pf[i], vf[j], o[i][j], 0, 0, 0);
      __builtin_amdgcn_s_setprio(0);
    }
  }

  // epilogue: normalize, pack via wave-private P rows, write gemm2 A-pack tiles
#pragma unroll
  for (int i = 0; i < 2; i++) {
    float inv[4];
#pragma unroll
    for (int r = 0; r < 4; r++) inv[r] = 1.0f / lsum[i][r];
#pragma unroll
    for (int r = 0; r < 4; r++) {
      int prow = wOff + i * 16 + lg * 4 + r;
#pragma unroll
      for (int j = 0; j < 8; j++)
        Ps[((j * 2 + (lq >> 3)) * 128 + prow) * 8 + (lq & 7)] = f2bf(o[i][j][r] * inv[r]);
    }
  }
#pragma unroll
  for (int it = 0; it < 8; it++) {
    int row_loc = it * 4 + (lane >> 4);
    int cc = lane & 15;
    short8 v = *(const short8*)(Ps + (cc * 128 + wOff + row_loc) * 8);
    long tb = ((long)qt * 64 + h * 2 + (cc >> 3)) * 8192;
    *(short8*)(aop + tb + ((cc & 7) * 128 + wOff + row_loc) * 8) = v;
  }
}

// -------------------- launcher --------------------
extern "C" void kernel_launch(void* const* d_in, const int* in_sizes, int n_in,
                              void* d_out, int out_size, void* d_ws, size_t ws_size,
                              hipStream_t stream) {
  (void)in_sizes; (void)n_in; (void)out_size;
  const float* hs = (const float*)d_in[0];
  // d_in[1] = attention_mask: deterministic causal, applied analytically
  const float* wp = (const float*)d_in[2];
  const float* wo = (const float*)d_in[3];
  float* out = (float*)d_out;
  char* ws = (char*)d_ws;

  unsigned short* Ap1  = (unsigned short*)(ws);                 // X pack    16 MiB  @0
  unsigned short* Bp1  = (unsigned short*)(ws + 16777216);      // Wp pack   96 MiB  @16M
  unsigned short* Bp2  = (unsigned short*)(ws + 117440512);     // Wo pack   32 MiB  @112M
  unsigned short* proj = (unsigned short*)(ws + 150994944);     // proj      48 MiB  @144M
  unsigned short* aop  = (unsigned short*)(ws + 201326592);     // ao pack   16 MiB  @192M
  unsigned short* Qf   = (unsigned short*)(ws);                 // reuse Ap1 (dead after gemm1)
  unsigned short* Kf   = (unsigned short*)(ws + 16777216);      // reuse Bp1 head
  unsigned short* Vf   = (unsigned short*)(ws + 33554432);      // reuse Bp1 +16M
  if (ws_size < 218103808) return;  // need ~208 MiB

  // Q rows of w_pack (rows < 4096) pre-scaled by (1/sqrt(128))*log2(e)
  pack_fp32<<<dim3(16, 64), 256, 0, stream>>>(hs, Ap1, HID, 0, 1.0f);
  pack_fp32<<<dim3(96, 64), 256, 0, stream>>>(wp, Bp1, HID, 4096, 0.12751744154f);
  pack_fp32<<<dim3(32, 64), 256, 0, stream>>>(wo, Bp2, HID, 0, 1.0f);

  gemm_pk<0><<<1536, 256, 0, stream>>>(Ap1, Bp1, (void*)proj, PROJN, HID);

  pack_qk<<<dim3(16, 32), 256, 0, stream>>>(proj, Qf, Kf);
  pack_v<<<dim3(16, 32), 256, 0, stream>>>(proj, Vf);

  attn_kernel<<<512, 256, 0, stream>>>(Qf, Kf, Vf, aop);

  gemm_pk<1><<<512, 256, 0, stream>>>(aop, Bp2, (void*)out, HID, HID);
}

// Round 2
// 776.511 us; speedup vs baseline: 1.1611x; 1.1611x over previous
//
#include <hip/hip_runtime.h>
#include <stdint.h>

typedef __attribute__((ext_vector_type(8))) short short8;
typedef __attribute__((ext_vector_type(4))) float floatx4;

#define SEQ    2048
#define HID    4096
#define NHEAD  32
#define HDIMV  128
#define PROJN  12288

__device__ __forceinline__ unsigned short f2bf(float f) {
  union { float f; unsigned u; } v; v.f = f;
  unsigned r = (v.u + 0x7fffu + ((v.u >> 16) & 1u)) >> 16;
  return (unsigned short)r;
}

// -------------------- async 16B global->LDS --------------------
__device__ __forceinline__ void g2l16(const void* g, void* l) {
  __builtin_amdgcn_global_load_lds(
      (const __attribute__((address_space(1))) void*)g,
      (__attribute__((address_space(3))) void*)l, 16, 0, 0);
}

// ---------- pack fp32 [R x K] row-major -> bf16 tile images ----------
// Tile (rp, kt) = 128 rows x 64 k, chunk-major: elem (r,c) at
// tile*8192 + ((c>>3)*128 + r)*8 + (c&7). Rows < scale_rows get multiplied by
// scale (used to fold the softmax 1/sqrt(d)*log2(e) into w_pack's Q rows).
__global__ __launch_bounds__(256) void pack_fp32(const float* __restrict__ src,
                                                 unsigned short* __restrict__ dst, int K,
                                                 int scale_rows, float scale) {
  const int rp = blockIdx.x, kt = blockIdx.y, t = threadIdx.x;
  const long tb = ((long)rp * gridDim.y + kt) * 8192;
#pragma unroll
  for (int j = 0; j < 4; j++) {
    int ch = t + j * 256;
    int r = ch & 127, cc = ch >> 7;
    float sc = (rp * 128 + r < scale_rows) ? scale : 1.0f;
    const float* s = src + (long)(rp * 128 + r) * K + kt * 64 + cc * 8;
    float4 a = *(const float4*)s;
    float4 b = *(const float4*)(s + 4);
    short8 o;
    o[0] = (short)f2bf(a.x * sc); o[1] = (short)f2bf(a.y * sc);
    o[2] = (short)f2bf(a.z * sc); o[3] = (short)f2bf(a.w * sc);
    o[4] = (short)f2bf(b.x * sc); o[5] = (short)f2bf(b.y * sc);
    o[6] = (short)f2bf(b.z * sc); o[7] = (short)f2bf(b.w * sc);
    *(short8*)(dst + tb + ch * 8) = o;
  }
}

// -------------------- NT GEMM on packed tiles (generic, for gemm2) ----------
template<int OUT_F32>
__global__ __launch_bounds__(256, 4) void gemm_pk(
    const unsigned short* __restrict__ Ap,
    const unsigned short* __restrict__ Bp,
    void* __restrict__ C, int N, int K) {
  __shared__ __align__(16) unsigned short As[8192];
  __shared__ __align__(16) unsigned short Bs[8192];
  const int t = threadIdx.x;
  const int wave = t >> 6, lane = t & 63;
  const int bid = blockIdx.x;
  const int xcd = bid & 7;
  const int li = bid >> 3;
  const int mi = li & 15;
  const int ni = (li >> 4) * 8 + xcd;
  const int KT = K >> 6;
  const unsigned short* at = Ap + (long)mi * KT * 8192 + t * 8;
  const unsigned short* bt = Bp + (long)ni * KT * 8192 + t * 8;
  unsigned short* asl = As + wave * 512;
  unsigned short* bsl = Bs + wave * 512;

  const int mw = (wave >> 1) * 64;
  const int nw = (wave & 1) * 64;
  const int lq = lane & 15, lg = lane >> 4;

  floatx4 zero = {0.f, 0.f, 0.f, 0.f};
  floatx4 acc[4][4];
  for (int i = 0; i < 4; i++)
    for (int j = 0; j < 4; j++) acc[i][j] = zero;

  for (int kt = 0; kt < KT; kt++) {
    __syncthreads();
    const unsigned short* ak = at + (long)kt * 8192;
    const unsigned short* bk = bt + (long)kt * 8192;
#pragma unroll
    for (int j = 0; j < 4; j++) g2l16(ak + j * 2048, asl + j * 2048);
#pragma unroll
    for (int j = 0; j < 4; j++) g2l16(bk + j * 2048, bsl + j * 2048);
    __syncthreads();
#pragma unroll
    for (int kk = 0; kk < 2; kk++) {
      const int ch = (kk * 4 + lg) * 1024;
      short8 af[4], bfr[4];
#pragma unroll
      for (int i = 0; i < 4; i++)
        af[i] = *(const short8*)(As + ch + (mw + i * 16 + lq) * 8);
#pragma unroll
      for (int j = 0; j < 4; j++)
        bfr[j] = *(const short8*)(Bs + ch + (nw + j * 16 + lq) * 8);
#pragma unroll
      for (int i = 0; i < 4; i++)
#pragma unroll
        for (int j = 0; j < 4; j++)
          acc[i][j] = __builtin_amdgcn_mfma_f32_16x16x32_bf16(af[i], bfr[j], acc[i][j], 0, 0, 0);
    }
  }

  const int row0 = mi * 128 + mw + lg * 4;
  const int col0 = ni * 128 + nw + lq;
  if (OUT_F32) {
    float* Cf = (float*)C;
#pragma unroll
    for (int i = 0; i < 4; i++)
#pragma unroll
      for (int j = 0; j < 4; j++)
#pragma unroll
        for (int r = 0; r < 4; r++)
          Cf[(long)(row0 + i * 16 + r) * N + col0 + j * 16] = acc[i][j][r];
  } else {
    unsigned short* Cb = (unsigned short*)C;
#pragma unroll
    for (int i = 0; i < 4; i++)
#pragma unroll
      for (int j = 0; j < 4; j++)
#pragma unroll
        for (int r = 0; r < 4; r++)
          Cb[(long)(row0 + i * 16 + r) * N + col0 + j * 16] = f2bf(acc[i][j][r]);
  }
}

// ---------- gemm1 with fused QKV re-pack epilogue ----------
// Output tile (mi, ni) of proj = X @ Wp^T maps exactly onto one packed tile:
//   ni in [ 0,32): Q head ni,    Qf tile (h*16 + mi), chunk-major (r=s_loc, c=d)
//   ni in [32,64): K head ni-32, Kf tile, same layout
//   ni in [64,96): V head ni-64, Vf tile, TRANSPOSED (row=d, k=s_loc)
// Chunk-major addr for elem (row,c): ((c>>3)*128 + row)*8 + (c&7).
// Scattered 2B stores; each block covers its full 16KB tile densely, so TCC
// write-combines (round-0 profile: WRITE_SIZE == logical bytes, no inflation).
__global__ __launch_bounds__(256, 4) void gemm_qkv(
    const unsigned short* __restrict__ Ap,
    const unsigned short* __restrict__ Bp,
    unsigned short* __restrict__ Qf,
    unsigned short* __restrict__ Kf,
    unsigned short* __restrict__ Vf) {
  __shared__ __align__(16) unsigned short As[8192];
  __shared__ __align__(16) unsigned short Bs[8192];
  const int t = threadIdx.x;
  const int wave = t >> 6, lane = t & 63;
  const int bid = blockIdx.x;
  const int xcd = bid & 7;
  const int li = bid >> 3;
  const int mi = li & 15;
  const int ni = (li >> 4) * 8 + xcd;
  const int KT = HID >> 6;
  const unsigned short* at = Ap + (long)mi * KT * 8192 + t * 8;
  const unsigned short* bt = Bp + (long)ni * KT * 8192 + t * 8;
  unsigned short* asl = As + wave * 512;
  unsigned short* bsl = Bs + wave * 512;

  const int mw = (wave >> 1) * 64;
  const int nw = (wave & 1) * 64;
  const int lq = lane & 15, lg = lane >> 4;

  floatx4 zero = {0.f, 0.f, 0.f, 0.f};
  floatx4 acc[4][4];
  for (int i = 0; i < 4; i++)
    for (int j = 0; j < 4; j++) acc[i][j] = zero;

  for (int kt = 0; kt < KT; kt++) {
    __syncthreads();
    const unsigned short* ak = at + (long)kt * 8192;
    const unsigned short* bk = bt + (long)kt * 8192;
#pragma unroll
    for (int j = 0; j < 4; j++) g2l16(ak + j * 2048, asl + j * 2048);
#pragma unroll
    for (int j = 0; j < 4; j++) g2l16(bk + j * 2048, bsl + j * 2048);
    __syncthreads();
#pragma unroll
    for (int kk = 0; kk < 2; kk++) {
      const int ch = (kk * 4 + lg) * 1024;
      short8 af[4], bfr[4];
#pragma unroll
      for (int i = 0; i < 4; i++)
        af[i] = *(const short8*)(As + ch + (mw + i * 16 + lq) * 8);
#pragma unroll
      for (int j = 0; j < 4; j++)
        bfr[j] = *(const short8*)(Bs + ch + (nw + j * 16 + lq) * 8);
#pragma unroll
      for (int i = 0; i < 4; i++)
#pragma unroll
        for (int j = 0; j < 4; j++)
          acc[i][j] = __builtin_amdgcn_mfma_f32_16x16x32_bf16(af[i], bfr[j], acc[i][j], 0, 0, 0);
    }
  }

  const int sec = ni >> 5;        // 0=Q, 1=K, 2=V
  const int h = ni & 31;
  unsigned short* dst =
      (sec == 0 ? Qf : (sec == 1 ? Kf : Vf)) + ((long)(h * 16 + mi)) * 16384;
  if (sec < 2) {
#pragma unroll
    for (int i = 0; i < 4; i++)
#pragma unroll
      for (int j = 0; j < 4; j++)
#pragma unroll
        for (int r = 0; r < 4; r++) {
          int row = mw + i * 16 + lg * 4 + r;      // local seq row
          int c = nw + j * 16 + lq;                // local head dim
          dst[((c >> 3) * 128 + row) * 8 + (c & 7)] = f2bf(acc[i][j][r]);
        }
  } else {
#pragma unroll
    for (int i = 0; i < 4; i++)
#pragma unroll
      for (int j = 0; j < 4; j++)
#pragma unroll
        for (int r = 0; r < 4; r++) {
          int s = mw + i * 16 + lg * 4 + r;        // local seq row (becomes k)
          int d = nw + j * 16 + lq;                // head dim (becomes row)
          dst[((s >> 3) * 128 + d) * 8 + (s & 7)] = f2bf(acc[i][j][r]);
        }
  }
}

// stage one contiguous 32KB packed tile into LDS (wave-cooperative, coalesced)
__device__ __forceinline__ void stage_tile(const unsigned short* g, unsigned short* lds,
                                           int wave, int lane) {
  const unsigned short* gp = g + wave * 4096 + lane * 8;
  unsigned short* lp = lds + wave * 4096;
#pragma unroll
  for (int j = 0; j < 8; j++) g2l16(gp + j * 512, lp + j * 512);
}

// -------------------- causal flash attention --------------------
// 512 blocks heavy-first: h = bx&31, qt = 15-(bx>>5). 4 waves, 32 q-rows each.
// K/V double-buffered in LDS (one barrier per kv iter, prefetch overlaps compute).
// Q frags in regs; P round-trip via wave-private 32KB LDS. Q pre-scaled (log2 dom).
__global__ __launch_bounds__(256, 1) void attn_kernel(
    const unsigned short* __restrict__ Qf,
    const unsigned short* __restrict__ Kf,
    const unsigned short* __restrict__ Vf,
    unsigned short* __restrict__ aop) {
  __shared__ __align__(16) unsigned short Ks[2][16384];
  __shared__ __align__(16) unsigned short Vs[2][16384];
  __shared__ __align__(16) unsigned short Ps[16384];
  const int bx = blockIdx.x;
  const int h = bx & 31;
  const int qt = 15 - (bx >> 5);
  const int t = threadIdx.x, wave = t >> 6, lane = t & 63;
  const int lq = lane & 15, lg = lane >> 4;
  const int wOff = wave * 32;

  // Q fragments: coalesced global reads from packed image (Q pre-scaled)
  const unsigned short* qb = Qf + ((long)(h * 16 + qt)) * 16384;
  short8 qf[2][4];
#pragma unroll
  for (int i = 0; i < 2; i++)
#pragma unroll
    for (int kk = 0; kk < 4; kk++)
      qf[i][kk] = *(const short8*)(qb + ((kk * 4 + lg) * 128 + wOff + i * 16 + lq) * 8);

  float mraw[2][4], lsum[2][4];
  floatx4 zero = {0.f, 0.f, 0.f, 0.f};
  floatx4 o[2][8];
#pragma unroll
  for (int i = 0; i < 2; i++)
#pragma unroll
    for (int r = 0; r < 4; r++) { mraw[i][r] = -INFINITY; lsum[i][r] = 0.f; }
#pragma unroll
  for (int i = 0; i < 2; i++)
#pragma unroll
    for (int j = 0; j < 8; j++) o[i][j] = zero;

  const unsigned short* kb0 = Kf + ((long)h * 16) * 16384;
  const unsigned short* vb0 = Vf + ((long)h * 16) * 16384;
  stage_tile(kb0, Ks[0], wave, lane);
  stage_tile(vb0, Vs[0], wave, lane);

  for (int kv = 0; kv <= qt; kv++) {
    const int cur = kv & 1;
    const bool diag = (kv == qt);
    __syncthreads();  // cur buffers staged; prev-iter LDS reads done
    if (!diag) {
      stage_tile(kb0 + (long)(kv + 1) * 16384, Ks[1 - cur], wave, lane);
      stage_tile(vb0 + (long)(kv + 1) * 16384, Vs[1 - cur], wave, lane);
    }

    // S = Q K^T (already in log2 domain via pre-scaled Q)
    floatx4 s[2][8];
#pragma unroll
    for (int i = 0; i < 2; i++)
#pragma unroll
      for (int j = 0; j < 8; j++) s[i][j] = zero;
#pragma unroll
    for (int kk = 0; kk < 4; kk++) {
      short8 bfr[8];
#pragma unroll
      for (int j = 0; j < 8; j++)
        bfr[j] = *(const short8*)(&Ks[cur][((kk * 4 + lg) * 128 + j * 16 + lq) * 8]);
#pragma unroll
      for (int i = 0; i < 2; i++)
#pragma unroll
        for (int j = 0; j < 8; j++)
          s[i][j] = __builtin_amdgcn_mfma_f32_16x16x32_bf16(qf[i][kk], bfr[j], s[i][j], 0, 0, 0);
    }

    if (diag) {
#pragma unroll
      for (int i = 0; i < 2; i++)
#pragma unroll
        for (int r = 0; r < 4; r++) {
          int qrow = qt * 128 + wOff + i * 16 + lg * 4 + r;
#pragma unroll
          for (int j = 0; j < 8; j++)
            if (kv * 128 + j * 16 + lq > qrow) s[i][j][r] = -INFINITY;
        }
    }

    // online softmax (log2 domain; rows lane-local, reduce over 16 col-lanes)
    float alpha_[2][4];
#pragma unroll
    for (int i = 0; i < 2; i++) {
#pragma unroll
      for (int r = 0; r < 4; r++) {
        float mx = s[i][0][r];
#pragma unroll
        for (int j = 1; j < 8; j++) mx = fmaxf(mx, s[i][j][r]);
#pragma unroll
        for (int d = 1; d < 16; d <<= 1) mx = fmaxf(mx, __shfl_xor(mx, d, 64));
        float mnew = fmaxf(mraw[i][r], mx);
        float al = exp2f(mraw[i][r] - mnew);
        float ps = 0.f;
#pragma unroll
        for (int j = 0; j < 8; j++) {
          float p = exp2f(s[i][j][r] - mnew);
          s[i][j][r] = p;
          ps += p;
        }
#pragma unroll
        for (int d = 1; d < 16; d <<= 1) ps += __shfl_xor(ps, d, 64);
        lsum[i][r] = lsum[i][r] * al + ps;
        mraw[i][r] = mnew;
        alpha_[i][r] = al;
      }
    }
#pragma unroll
    for (int i = 0; i < 2; i++)
#pragma unroll
      for (int j = 0; j < 8; j++)
#pragma unroll
        for (int r = 0; r < 4; r++) o[i][j][r] *= alpha_[i][r];

    // P (C-layout regs) -> chunk-major LDS, wave-private rows, no barrier
#pragma unroll
    for (int i = 0; i < 2; i++)
#pragma unroll
      for (int r = 0; r < 4; r++) {
        int prow = wOff + i * 16 + lg * 4 + r;
#pragma unroll
        for (int j = 0; j < 8; j++)
          Ps[((j * 2 + (lq >> 3)) * 128 + prow) * 8 + (lq & 7)] = f2bf(s[i][j][r]);
      }

    // O += P V (A-frags from own P rows, B-frags from Vs tile in LDS)
#pragma unroll
    for (int kk = 0; kk < 4; kk++) {
      short8 pf[2], vf[8];
#pragma unroll
      for (int i = 0; i < 2; i++)
        pf[i] = *(const short8*)(Ps + ((kk * 4 + lg) * 128 + wOff + i * 16 + lq) * 8);
#pragma unroll
      for (int j = 0; j < 8; j++)
        vf[j] = *(const short8*)(&Vs[cur][((kk * 4 + lg) * 128 + j * 16 + lq) * 8]);
#pragma unroll
      for (int i = 0; i < 2; i++)
#pragma unroll
        for (int j = 0; j < 8; j++)
          o[i][j] = __builtin_amdgcn_mfma_f32_16x16x32_bf16(pf[i], vf[j], o[i][j], 0, 0, 0);
    }
  }

  // epilogue: normalize, pack via wave-private P rows, write gemm2 A-pack tiles
#pragma unroll
  for (int i = 0; i < 2; i++) {
    float inv[4];
#pragma unroll
    for (int r = 0; r < 4; r++) inv[r] = 1.0f / lsum[i][r];
#pragma unroll
    for (int r = 0; r < 4; r++) {
      int prow = wOff + i * 16 + lg * 4 + r;
#pragma unroll
      for (int j = 0; j < 8; j++)
        Ps[((j * 2 + (lq >> 3)) * 128 + prow) * 8 + (lq & 7)] = f2bf(o[i][j][r] * inv[r]);
    }
  }
#pragma unroll
  for (int it = 0; it < 8; it++) {
    int row_loc = it * 4 + (lane >> 4);
    int cc = lane & 15;
    short8 v = *(const short8*)(Ps + (cc * 128 + wOff + row_loc) * 8);
    long tb = ((long)qt * 64 + h * 2 + (cc >> 3)) * 8192;
    *(short8*)(aop + tb + ((cc & 7) * 128 + wOff + row_loc) * 8) = v;
  }
}

// -------------------- launcher --------------------
extern "C" void kernel_launch(void* const* d_in, const int* in_sizes, int n_in,
                              void* d_out, int out_size, void* d_ws, size_t ws_size,
                              hipStream_t stream) {
  (void)in_sizes; (void)n_in; (void)out_size;
  const float* hs = (const float*)d_in[0];
  // d_in[1] = attention_mask: deterministic causal, applied analytically
  const float* wp = (const float*)d_in[2];
  const float* wo = (const float*)d_in[3];
  float* out = (float*)d_out;
  char* ws = (char*)d_ws;

  unsigned short* Ap1 = (unsigned short*)(ws);                 // X pack    16 MiB  @0
  unsigned short* Bp1 = (unsigned short*)(ws + 16777216);      // Wp pack   96 MiB  @16M
  unsigned short* Bp2 = (unsigned short*)(ws + 117440512);     // Wo pack   32 MiB  @112M
  unsigned short* Qf  = (unsigned short*)(ws + 150994944);     // Q pack    16 MiB  @144M
  unsigned short* Kf  = (unsigned short*)(ws + 167772160);     // K pack    16 MiB  @160M
  unsigned short* Vf  = (unsigned short*)(ws + 184549376);     // V^T pack  16 MiB  @176M
  unsigned short* aop = (unsigned short*)(ws + 201326592);     // ao pack   16 MiB  @192M
  if (ws_size < 218103808) return;  // need ~208 MiB

  // Q rows of w_pack (rows < 4096) pre-scaled by (1/sqrt(128))*log2(e)
  pack_fp32<<<dim3(16, 64), 256, 0, stream>>>(hs, Ap1, HID, 0, 1.0f);
  pack_fp32<<<dim3(96, 64), 256, 0, stream>>>(wp, Bp1, HID, 4096, 0.12751744154f);
  pack_fp32<<<dim3(32, 64), 256, 0, stream>>>(wo, Bp2, HID, 0, 1.0f);

  gemm_qkv<<<1536, 256, 0, stream>>>(Ap1, Bp1, Qf, Kf, Vf);

  attn_kernel<<<512, 256, 0, stream>>>(Qf, Kf, Vf, aop);

  gemm_pk<1><<<512, 256, 0, stream>>>(aop, Bp2, (void*)out, HID, HID);
}